// Round 7
// baseline (470.750 us; speedup 1.0000x reference)
//
#include <hip/hip_runtime.h>
#include <hip/hip_bf16.h>

// Problem sizes (fixed by the reference)
#define NNODES 50000   // 3125 * 16 -> exact 16-row MFMA tiles
#define NEDGES 800000
#define NF 256         // input features
#define NH 128         // hidden
#define BN_EPS 1e-5f
#define MTILES (NNODES / 16)                 // 3125
#define GEMM_BLOCKS 512                      // gemm_in grid
#define GCONV_BLOCKS 512                     // fused gather+conv grid
#define NBUCKETS 196                         // ceil(NNODES / 256)
#define BCAP 4608                            // bucket capacity: mean 4096 + 8 sigma
#define SCAT_BLOCKS ((NEDGES + 2047) / 2048) // 391

typedef __attribute__((ext_vector_type(8))) __bf16 bf16x8;  // MFMA A/B frag (4 VGPRs)
typedef __attribute__((ext_vector_type(4))) float floatx4;  // MFMA C/D frag

__device__ __forceinline__ __hip_bfloat16 f2bf(float f) { return __float2bfloat16(f); }

// load 8 consecutive fp32, round to bf16x8 MFMA fragment
__device__ __forceinline__ bf16x8 cvt8(const float* __restrict__ p) {
    floatx4 a0 = *(const floatx4*)p;
    floatx4 a1 = *(const floatx4*)(p + 4);
    bf16x8 r;
    r[0] = (__bf16)a0[0]; r[1] = (__bf16)a0[1]; r[2] = (__bf16)a0[2]; r[3] = (__bf16)a0[3];
    r[4] = (__bf16)a1[0]; r[5] = (__bf16)a1[1]; r[6] = (__bf16)a1[2]; r[7] = (__bf16)a1[3];
    return r;
}

// ---------------------------------------------------------------------------
// One-shot weight conversion fp32 -> bf16 into contiguous wbf:
// [W_in 32768 | W1r 16384 | W1o 16384 | W2r 16384 | W2o 16384]
// Block 0 also initializes the bucket cursors to their fixed-stride bases.
// ---------------------------------------------------------------------------
__global__ __launch_bounds__(256) void convert_w_kernel(
    const float* __restrict__ W_in, const float* __restrict__ W1r,
    const float* __restrict__ W1o, const float* __restrict__ W2r,
    const float* __restrict__ W2o, __hip_bfloat16* __restrict__ wbf,
    int* __restrict__ gcursor)
{
    const int i = blockIdx.x * 256 + threadIdx.x;   // grid sized exactly 98304
    if (blockIdx.x == 0 && threadIdx.x < NBUCKETS)
        gcursor[threadIdx.x] = threadIdx.x * BCAP;
    const float* src; int off;
    if (i < 32768)      { src = W_in; off = i; }
    else if (i < 49152) { src = W1r;  off = i - 32768; }
    else if (i < 65536) { src = W1o;  off = i - 49152; }
    else if (i < 81920) { src = W2r;  off = i - 65536; }
    else                { src = W2o;  off = i - 81920; }
    wbf[i] = f2bf(src[off]);
}

// ---------------------------------------------------------------------------
// CSR level 1: bucket edges by dst>>8 into fixed-stride regions.
// ---------------------------------------------------------------------------
__global__ __launch_bounds__(256) void bucket_scatter_kernel(
    const int* __restrict__ adj, const float* __restrict__ ew,
    int* __restrict__ gcursor, uint2* __restrict__ pairbuf,
    unsigned char* __restrict__ nodebuf)
{
    __shared__ int cnt[NBUCKETS];
    __shared__ int base[NBUCKETS];
    const int tid = threadIdx.x;
    if (tid < NBUCKETS) cnt[tid] = 0;
    __syncthreads();
    const int e0 = blockIdx.x * 2048;
    #pragma unroll
    for (int i = 0; i < 8; ++i) {
        const int e = e0 + i * 256 + tid;
        if (e < NEDGES) atomicAdd(&cnt[adj[NEDGES + e] >> 8], 1);
    }
    __syncthreads();
    if (tid < NBUCKETS) {
        base[tid] = atomicAdd(&gcursor[tid], cnt[tid]);
        cnt[tid] = 0;
    }
    __syncthreads();
    #pragma unroll
    for (int i = 0; i < 8; ++i) {
        const int e = e0 + i * 256 + tid;
        if (e >= NEDGES) continue;
        const int dst = adj[NEDGES + e];
        const int b = dst >> 8;
        const int off = atomicAdd(&cnt[b], 1);
        const int slot = base[b] + off;
        if (slot < (b + 1) * BCAP) {          // overflow guard (P ~ 1e-10)
            pairbuf[slot] = make_uint2((unsigned)adj[e], __float_as_uint(ew[e]));
            nodebuf[slot] = (unsigned char)(dst & 255);
        }
    }
}

// ---------------------------------------------------------------------------
// CSR level 2: one block per bucket; counting sort by node within bucket.
// ---------------------------------------------------------------------------
__global__ __launch_bounds__(256) void bucket_sort_kernel(
    const int* __restrict__ gcursor, const uint2* __restrict__ pairbuf,
    const unsigned char* __restrict__ nodebuf, uint2* __restrict__ sorted,
    int* __restrict__ rowptr, int* __restrict__ rowend)
{
    const int b = blockIdx.x;
    const int tid = threadIdx.x;
    const int capbase = b * BCAP;
    int n = gcursor[b] - capbase;
    if (n > BCAP) n = BCAP;

    __shared__ int cnt[256];
    __shared__ int s[256];
    cnt[tid] = 0;
    __syncthreads();
    for (int j = tid; j < n; j += 256)
        atomicAdd(&cnt[nodebuf[capbase + j]], 1);
    __syncthreads();
    const int v = cnt[tid];
    s[tid] = v;
    __syncthreads();
    for (int off = 1; off < 256; off <<= 1) {
        const int t = (tid >= off) ? s[tid - off] : 0;
        __syncthreads();
        s[tid] += t;
        __syncthreads();
    }
    const int excl = s[tid] - v;
    const int node = b * 256 + tid;
    if (node < NNODES) {
        rowptr[node] = capbase + excl;
        rowend[node] = capbase + excl + v;
    }
    cnt[tid] = excl;                          // reuse as scatter cursor
    __syncthreads();
    for (int j = tid; j < n; j += 256) {
        const int nd = nodebuf[capbase + j];
        const int pos = atomicAdd(&cnt[nd], 1);
        sorted[capbase + pos] = pairbuf[capbase + j];
    }
}

// ---------------------------------------------------------------------------
// h0 = relu(X[N,256] @ W[128,256]^T + b) -> bf16. Register-resident weights.
// ---------------------------------------------------------------------------
__global__ __launch_bounds__(256, 2) void gemm_in_kernel(
    const float* __restrict__ X, const __hip_bfloat16* __restrict__ W,
    const float* __restrict__ bias, __hip_bfloat16* __restrict__ out)
{
    const int waveG = blockIdx.x * 4 + (threadIdx.x >> 6);  // 0..2047
    const int lane = threadIdx.x & 63;
    const int half = waveG & 1;
    const int ar = lane & 15;
    const int q  = lane >> 4;

    bf16x8 bw[4][8];
    float bv[4];
    #pragma unroll
    for (int t = 0; t < 4; ++t) {
        const int row = half * 64 + t * 16 + ar;
        bv[t] = bias[row];
        #pragma unroll
        for (int k = 0; k < 8; ++k)
            bw[t][k] = *(const bf16x8*)(W + (size_t)row * NF + k * 32 + q * 8);
    }

    for (int strip = waveG >> 1; strip < MTILES; strip += GEMM_BLOCKS * 2) {
        const int m0 = strip << 4;
        floatx4 acc[4] = {};
        #pragma unroll
        for (int k = 0; k < 8; ++k) {
            const bf16x8 a = cvt8(X + (size_t)(m0 + ar) * NF + k * 32 + q * 8);
            #pragma unroll
            for (int t = 0; t < 4; ++t)
                acc[t] = __builtin_amdgcn_mfma_f32_16x16x32_bf16(a, bw[t][k], acc[t], 0, 0, 0);
        }
        #pragma unroll
        for (int t = 0; t < 4; ++t) {
            const int col = half * 64 + t * 16 + ar;
            #pragma unroll
            for (int r = 0; r < 4; ++r) {
                const float v = fmaxf(acc[t][r] + bv[t], 0.f);
                out[(size_t)(m0 + q * 4 + r) * NH + col] = f2bf(v);
            }
        }
    }
}

// ---------------------------------------------------------------------------
// FUSED gather + conv:
//   agg[n] = sum_e w_e h[src_e];  t = agg @ Wrel^T + h @ Wroot^T + b
// Block = 16-node strip (grid-stride). Wave u gathers A-frag of kstep u
// directly in fragment layout (lane(ar,q) accumulates feats 32u+8q..+8 of
// node m0+ar), exchanges frags via LDS, then computes 2 column tiles with
// register-resident weights. Fused column stats -> partial.
// ---------------------------------------------------------------------------
__global__ __launch_bounds__(256, 3) void gconv_kernel(
    const uint2* __restrict__ sorted, const int* __restrict__ rowptr,
    const int* __restrict__ rowend, const __hip_bfloat16* __restrict__ h,
    const __hip_bfloat16* __restrict__ Wrel, const __hip_bfloat16* __restrict__ Wroot,
    const float* __restrict__ bias, float* __restrict__ out,
    float* __restrict__ partial)
{
    const int u    = threadIdx.x >> 6;   // wave id == owned kstep
    const int lane = threadIdx.x & 63;
    const int ar   = lane & 15;
    const int q    = lane >> 4;

    // register-resident weights: tiles {2u, 2u+1}, 4 ksteps, both chains
    bf16x8 brel[2][4], brt[2][4];
    float bv[2];
    #pragma unroll
    for (int tt = 0; tt < 2; ++tt) {
        const int row = (2 * u + tt) * 16 + ar;
        bv[tt] = bias[row];
        #pragma unroll
        for (int k = 0; k < 4; ++k) {
            brel[tt][k] = *(const bf16x8*)(Wrel + (size_t)row * NH + k * 32 + q * 8);
            brt[tt][k]  = *(const bf16x8*)(Wroot + (size_t)row * NH + k * 32 + q * 8);
        }
    }

    __shared__ __hip_bfloat16 fragbuf[4 * 512];  // 4 ksteps x 64 lanes x 8 bf16
    __shared__ float sst[256];

    float s1[2] = {}, s2[2] = {};
    const int feat_off = u * 32 + q * 8;

    for (int s = blockIdx.x; s < MTILES; s += GCONV_BLOCKS) {
        const int m0 = s << 4;
        const int node = m0 + ar;

        // ---- gather phase: accumulate 8 feats (kstep u) of node m0+ar ----
        int cur = rowptr[node];
        const int end = rowend[node];
        float ga[8] = {};
        while (__any(cur < end)) {
            if (cur < end) {
                const uint2 ev = sorted[cur++];
                const float w = __uint_as_float(ev.y);
                const bf16x8 c = *(const bf16x8*)(h + (size_t)ev.x * NH + feat_off);
                #pragma unroll
                for (int i = 0; i < 8; ++i) ga[i] += w * (float)c[i];
            }
        }
        bf16x8 myfrag;
        #pragma unroll
        for (int i = 0; i < 8; ++i) myfrag[i] = (__bf16)ga[i];
        *(bf16x8*)(fragbuf + u * 512 + lane * 8) = myfrag;
        __syncthreads();

        // ---- compute phase: 2 column tiles, both chains ----
        floatx4 acc[2] = {};
        #pragma unroll
        for (int k = 0; k < 4; ++k) {
            const bf16x8 a = *(const bf16x8*)(fragbuf + k * 512 + lane * 8);
            acc[0] = __builtin_amdgcn_mfma_f32_16x16x32_bf16(a, brel[0][k], acc[0], 0, 0, 0);
            acc[1] = __builtin_amdgcn_mfma_f32_16x16x32_bf16(a, brel[1][k], acc[1], 0, 0, 0);
        }
        #pragma unroll
        for (int k = 0; k < 4; ++k) {
            const bf16x8 a = *(const bf16x8*)(h + (size_t)(m0 + ar) * NH + k * 32 + q * 8);
            acc[0] = __builtin_amdgcn_mfma_f32_16x16x32_bf16(a, brt[0][k], acc[0], 0, 0, 0);
            acc[1] = __builtin_amdgcn_mfma_f32_16x16x32_bf16(a, brt[1][k], acc[1], 0, 0, 0);
        }
        #pragma unroll
        for (int tt = 0; tt < 2; ++tt) {
            const int col = (2 * u + tt) * 16 + ar;
            #pragma unroll
            for (int r = 0; r < 4; ++r) {
                const float v = acc[tt][r] + bv[tt];
                out[(size_t)(m0 + q * 4 + r) * NH + col] = v;
                s1[tt] += v; s2[tt] += v * v;
            }
        }
        __syncthreads();   // protect fragbuf before next strip's writes
    }

    // ---- stats epilogue ----
    sst[threadIdx.x] = 0.f;
    __syncthreads();
    #pragma unroll
    for (int tt = 0; tt < 2; ++tt) {
        float a = s1[tt], b = s2[tt];
        a += __shfl_xor(a, 16, 64); a += __shfl_xor(a, 32, 64);
        b += __shfl_xor(b, 16, 64); b += __shfl_xor(b, 32, 64);
        if (q == 0) {
            const int col = (2 * u + tt) * 16 + ar;
            atomicAdd(&sst[col], a);
            atomicAdd(&sst[128 + col], b);
        }
    }
    __syncthreads();
    partial[blockIdx.x * 256 + threadIdx.x] = sst[threadIdx.x];
}

// ---------------------------------------------------------------------------
// stats[c] = sum over blocks of partial[b][c]
// ---------------------------------------------------------------------------
__global__ __launch_bounds__(256) void reduce_stats_kernel(
    const float* __restrict__ partial, float* __restrict__ stats)
{
    const int tid = threadIdx.x;
    float a = 0.f, b = 0.f, c = 0.f, d = 0.f;
    for (int blk = 0; blk < GCONV_BLOCKS; blk += 4) {
        a += partial[(blk + 0) * 256 + tid];
        b += partial[(blk + 1) * 256 + tid];
        c += partial[(blk + 2) * 256 + tid];
        d += partial[(blk + 3) * 256 + tid];
    }
    stats[tid] = (a + b) + (c + d);
}

// ---------------------------------------------------------------------------
// BN normalize variants
// ---------------------------------------------------------------------------
__global__ __launch_bounds__(256) void bn_relu_bf16_kernel(
    const float* __restrict__ t, const float* __restrict__ stats,
    const float* __restrict__ gamma, const float* __restrict__ beta,
    __hip_bfloat16* __restrict__ out)
{
    const size_t i = (size_t)blockIdx.x * blockDim.x + threadIdx.x;  // exact grid
    const int c = (int)(i & (NH - 1));
    const float inv_n = 1.0f / (float)NNODES;
    const float mu = stats[c] * inv_n;
    const float var = stats[128 + c] * inv_n - mu * mu;
    const float rs = rsqrtf(var + BN_EPS);
    float v = (t[i] - mu) * rs * gamma[c] + beta[c];
    out[i] = f2bf(fmaxf(v, 0.f));
}

__global__ __launch_bounds__(256) void bn_f32_kernel(
    const float* __restrict__ t, const float* __restrict__ stats,
    const float* __restrict__ gamma, const float* __restrict__ beta,
    float* __restrict__ out)
{
    const size_t i = (size_t)blockIdx.x * blockDim.x + threadIdx.x;
    const int c = (int)(i & (NH - 1));
    const float inv_n = 1.0f / (float)NNODES;
    const float mu = stats[c] * inv_n;
    const float var = stats[128 + c] * inv_n - mu * mu;
    const float rs = rsqrtf(var + BN_EPS);
    out[i] = (t[i] - mu) * rs * gamma[c] + beta[c];
}

// ---------------------------------------------------------------------------

extern "C" void kernel_launch(void* const* d_in, const int* in_sizes, int n_in,
                              void* d_out, int out_size, void* d_ws, size_t ws_size,
                              hipStream_t stream)
{
    const float* x    = (const float*)d_in[0];
    const int*   adj  = (const int*)d_in[1];
    const float* ew   = (const float*)d_in[2];
    const float* W_in = (const float*)d_in[3];
    const float* b_in = (const float*)d_in[4];
    const float* W1r  = (const float*)d_in[5];
    const float* b1   = (const float*)d_in[6];
    const float* W1o  = (const float*)d_in[7];
    const float* W2r  = (const float*)d_in[8];
    const float* b2   = (const float*)d_in[9];
    const float* W2o  = (const float*)d_in[10];
    const float* gmm  = (const float*)d_in[11];
    const float* bta  = (const float*)d_in[12];
    float* out = (float*)d_out;          // fp32 output [N, NH]
    float* t   = (float*)d_out;          // pre-BN conv result lives in d_out

    char* ws = (char*)d_ws;
    __hip_bfloat16* h0  = (__hip_bfloat16*)ws; ws += (size_t)NNODES * NH * 2;  // 12.8 MB
    __hip_bfloat16* h1  = (__hip_bfloat16*)ws; ws += (size_t)NNODES * NH * 2;  // 12.8 MB
    uint2*          sorted  = (uint2*)ws;      ws += (size_t)NBUCKETS * BCAP * 8;  // 7.2 MB
    uint2*          pairbuf = (uint2*)ws;      ws += (size_t)NBUCKETS * BCAP * 8;  // 7.2 MB
    unsigned char*  nodebuf = (unsigned char*)ws; ws += (size_t)NBUCKETS * BCAP;   // 0.9 MB
    int*            rowptr  = (int*)ws;        ws += NNODES * 4;
    int*            rowend  = (int*)ws;        ws += NNODES * 4;
    int*            gcursor = (int*)ws;        ws += ((NBUCKETS + 3) & ~3) * 4;
    __hip_bfloat16* wbf     = (__hip_bfloat16*)ws; ws += 98304 * 2;            // 192 KB
    float*          partial = (float*)ws;      ws += GCONV_BLOCKS * 256 * 4;   // 512 KB
    float*          st      = (float*)ws;      ws += 256 * 4;

    const __hip_bfloat16* Wb_in = wbf;
    const __hip_bfloat16* Wb1r  = wbf + 32768;
    const __hip_bfloat16* Wb1o  = wbf + 49152;
    const __hip_bfloat16* Wb2r  = wbf + 65536;
    const __hip_bfloat16* Wb2o  = wbf + 81920;

    const int bn_blocks = (NNODES * NH) / 256;                  // 25000

    // ---- prep: weight conversion (+ cursor init) + two-level bucket CSR ----
    convert_w_kernel<<<98304 / 256, 256, 0, stream>>>(W_in, W1r, W1o, W2r, W2o, wbf, gcursor);
    bucket_scatter_kernel<<<SCAT_BLOCKS, 256, 0, stream>>>(adj, ew, gcursor, pairbuf, nodebuf);
    bucket_sort_kernel<<<NBUCKETS, 256, 0, stream>>>(gcursor, pairbuf, nodebuf,
                                                     sorted, rowptr, rowend);

    // ---- layer 1 ----
    gemm_in_kernel<<<GEMM_BLOCKS, 256, 0, stream>>>(x, Wb_in, b_in, h0);
    gconv_kernel<<<GCONV_BLOCKS, 256, 0, stream>>>(sorted, rowptr, rowend, h0,
                                                   Wb1r, Wb1o, b1, t, partial);
    reduce_stats_kernel<<<1, 256, 0, stream>>>(partial, st);
    bn_relu_bf16_kernel<<<bn_blocks, 256, 0, stream>>>(t, st, gmm, bta, h1);

    // ---- layer 2 ----
    gconv_kernel<<<GCONV_BLOCKS, 256, 0, stream>>>(sorted, rowptr, rowend, h1,
                                                   Wb2r, Wb2o, b2, t, partial);
    reduce_stats_kernel<<<1, 256, 0, stream>>>(partial, st);
    bn_f32_kernel<<<bn_blocks, 256, 0, stream>>>(t, st, gmm, bta, out);
}

// Round 8
// 326.969 us; speedup vs baseline: 1.4397x; 1.4397x over previous
//
#include <hip/hip_runtime.h>
#include <hip/hip_bf16.h>

// Problem sizes (fixed by the reference)
#define NNODES 50000   // 3125 * 16 -> exact 16-row MFMA tiles
#define NEDGES 800000
#define NF 256         // input features
#define NH 128         // hidden
#define BN_EPS 1e-5f
#define MTILES (NNODES / 16)                 // 3125
#define GEMM_BLOCKS 512                      // 2048 waves
#define NBUCKETS 196                         // ceil(NNODES / 256)
#define BCAP 4608                            // bucket capacity: mean 4096 + 8 sigma
#define SCAT_BLOCKS ((NEDGES + 2047) / 2048) // 391

typedef __attribute__((ext_vector_type(8))) __bf16 bf16x8;  // MFMA A/B frag (4 VGPRs)
typedef __attribute__((ext_vector_type(4))) float floatx4;  // MFMA C/D frag

__device__ __forceinline__ __hip_bfloat16 f2bf(float f) { return __float2bfloat16(f); }
__device__ __forceinline__ float bits2f(unsigned short b) {
    union { unsigned u; float f; } u; u.u = ((unsigned)b) << 16; return u.f;
}

// load 8 consecutive fp32, round to bf16x8 MFMA fragment
__device__ __forceinline__ bf16x8 cvt8(const float* __restrict__ p) {
    floatx4 a0 = *(const floatx4*)p;
    floatx4 a1 = *(const floatx4*)(p + 4);
    bf16x8 r;
    r[0] = (__bf16)a0[0]; r[1] = (__bf16)a0[1]; r[2] = (__bf16)a0[2]; r[3] = (__bf16)a0[3];
    r[4] = (__bf16)a1[0]; r[5] = (__bf16)a1[1]; r[6] = (__bf16)a1[2]; r[7] = (__bf16)a1[3];
    return r;
}

// ---------------------------------------------------------------------------
// One-shot weight conversion fp32 -> bf16 into contiguous wbf.
// Block 0 inits bucket cursors; block 1 zeroes the two stats buffers.
// ---------------------------------------------------------------------------
__global__ __launch_bounds__(256) void convert_w_kernel(
    const float* __restrict__ W_in, const float* __restrict__ W1r,
    const float* __restrict__ W1o, const float* __restrict__ W2r,
    const float* __restrict__ W2o, __hip_bfloat16* __restrict__ wbf,
    int* __restrict__ gcursor, float* __restrict__ st1, float* __restrict__ st2)
{
    const int i = blockIdx.x * 256 + threadIdx.x;   // grid sized exactly 98304
    if (blockIdx.x == 0 && threadIdx.x < NBUCKETS)
        gcursor[threadIdx.x] = threadIdx.x * BCAP;
    if (blockIdx.x == 1) { st1[threadIdx.x] = 0.f; st2[threadIdx.x] = 0.f; }
    const float* src; int off;
    if (i < 32768)      { src = W_in; off = i; }
    else if (i < 49152) { src = W1r;  off = i - 32768; }
    else if (i < 65536) { src = W1o;  off = i - 49152; }
    else if (i < 81920) { src = W2r;  off = i - 65536; }
    else                { src = W2o;  off = i - 81920; }
    wbf[i] = f2bf(src[off]);
}

// ---------------------------------------------------------------------------
// CSR level 1: bucket edges by dst>>8 into fixed-stride regions.
// ---------------------------------------------------------------------------
__global__ __launch_bounds__(256) void bucket_scatter_kernel(
    const int* __restrict__ adj, const float* __restrict__ ew,
    int* __restrict__ gcursor, uint2* __restrict__ pairbuf,
    unsigned char* __restrict__ nodebuf)
{
    __shared__ int cnt[NBUCKETS];
    __shared__ int base[NBUCKETS];
    const int tid = threadIdx.x;
    if (tid < NBUCKETS) cnt[tid] = 0;
    __syncthreads();
    const int e0 = blockIdx.x * 2048;
    #pragma unroll
    for (int i = 0; i < 8; ++i) {
        const int e = e0 + i * 256 + tid;
        if (e < NEDGES) atomicAdd(&cnt[adj[NEDGES + e] >> 8], 1);
    }
    __syncthreads();
    if (tid < NBUCKETS) {
        base[tid] = atomicAdd(&gcursor[tid], cnt[tid]);
        cnt[tid] = 0;
    }
    __syncthreads();
    #pragma unroll
    for (int i = 0; i < 8; ++i) {
        const int e = e0 + i * 256 + tid;
        if (e >= NEDGES) continue;
        const int dst = adj[NEDGES + e];
        const int b = dst >> 8;
        const int off = atomicAdd(&cnt[b], 1);
        const int slot = base[b] + off;
        if (slot < (b + 1) * BCAP) {          // overflow guard (P ~ 1e-10)
            pairbuf[slot] = make_uint2((unsigned)adj[e], __float_as_uint(ew[e]));
            nodebuf[slot] = (unsigned char)(dst & 255);
        }
    }
}

// ---------------------------------------------------------------------------
// CSR level 2: one block per bucket; counting sort by node within bucket.
// ---------------------------------------------------------------------------
__global__ __launch_bounds__(256) void bucket_sort_kernel(
    const int* __restrict__ gcursor, const uint2* __restrict__ pairbuf,
    const unsigned char* __restrict__ nodebuf, uint2* __restrict__ sorted,
    int* __restrict__ rowptr, int* __restrict__ rowend)
{
    const int b = blockIdx.x;
    const int tid = threadIdx.x;
    const int capbase = b * BCAP;
    int n = gcursor[b] - capbase;
    if (n > BCAP) n = BCAP;

    __shared__ int cnt[256];
    __shared__ int s[256];
    cnt[tid] = 0;
    __syncthreads();
    for (int j = tid; j < n; j += 256)
        atomicAdd(&cnt[nodebuf[capbase + j]], 1);
    __syncthreads();
    const int v = cnt[tid];
    s[tid] = v;
    __syncthreads();
    for (int off = 1; off < 256; off <<= 1) {
        const int t = (tid >= off) ? s[tid - off] : 0;
        __syncthreads();
        s[tid] += t;
        __syncthreads();
    }
    const int excl = s[tid] - v;
    const int node = b * 256 + tid;
    if (node < NNODES) {
        rowptr[node] = capbase + excl;
        rowend[node] = capbase + excl + v;
    }
    cnt[tid] = excl;                          // reuse as scatter cursor
    __syncthreads();
    for (int j = tid; j < n; j += 256) {
        const int nd = nodebuf[capbase + j];
        const int pos = atomicAdd(&cnt[nd], 1);
        sorted[capbase + pos] = pairbuf[capbase + j];
    }
}

// ---------------------------------------------------------------------------
// h0 = relu(X[N,256] @ W[128,256]^T + b) -> bf16. Register-resident weights.
// ---------------------------------------------------------------------------
__global__ __launch_bounds__(256, 2) void gemm_in_kernel(
    const float* __restrict__ X, const __hip_bfloat16* __restrict__ W,
    const float* __restrict__ bias, __hip_bfloat16* __restrict__ out)
{
    const int waveG = blockIdx.x * 4 + (threadIdx.x >> 6);  // 0..2047
    const int lane = threadIdx.x & 63;
    const int half = waveG & 1;
    const int ar = lane & 15;
    const int q  = lane >> 4;

    bf16x8 bw[4][8];
    float bv[4];
    #pragma unroll
    for (int t = 0; t < 4; ++t) {
        const int row = half * 64 + t * 16 + ar;
        bv[t] = bias[row];
        #pragma unroll
        for (int k = 0; k < 8; ++k)
            bw[t][k] = *(const bf16x8*)(W + (size_t)row * NF + k * 32 + q * 8);
    }

    for (int strip = waveG >> 1; strip < MTILES; strip += GEMM_BLOCKS * 2) {
        const int m0 = strip << 4;
        floatx4 acc[4] = {};
        #pragma unroll
        for (int k = 0; k < 8; ++k) {
            const bf16x8 a = cvt8(X + (size_t)(m0 + ar) * NF + k * 32 + q * 8);
            #pragma unroll
            for (int t = 0; t < 4; ++t)
                acc[t] = __builtin_amdgcn_mfma_f32_16x16x32_bf16(a, bw[t][k], acc[t], 0, 0, 0);
        }
        #pragma unroll
        for (int t = 0; t < 4; ++t) {
            const int col = half * 64 + t * 16 + ar;
            #pragma unroll
            for (int r = 0; r < 4; ++r) {
                const float v = fmaxf(acc[t][r] + bv[t], 0.f);
                out[(size_t)(m0 + q * 4 + r) * NH + col] = f2bf(v);
            }
        }
    }
}

// ---------------------------------------------------------------------------
// Gather-reduce: agg[n] = sum_{e in CSR[n]} w_e * h[src_e]   (bf16 out)
// One wave per node, 2 feats/lane, 8-way edge unroll (independent loads).
// ---------------------------------------------------------------------------
__global__ __launch_bounds__(256) void gather_kernel(
    const uint2* __restrict__ sorted, const int* __restrict__ rowptr,
    const int* __restrict__ rowend,
    const __hip_bfloat16* __restrict__ h, __hip_bfloat16* __restrict__ agg)
{
    const int node = blockIdx.x * 4 + (threadIdx.x >> 6);
    if (node >= NNODES) return;
    const int lane = threadIdx.x & 63;
    const int beg = rowptr[node];
    const int end = rowend[node];
    const unsigned short* hb = (const unsigned short*)h;

    float a0[8] = {}, a1[8] = {};

    int j = beg;
    if ((j & 1) && j < end) {  // align to even index for uint4 loads
        const uint2 ev = sorted[j++];
        const float w = __uint_as_float(ev.y);
        const unsigned raw = *(const unsigned*)(hb + (size_t)ev.x * NH + lane * 2);
        a0[0] += w * bits2f((unsigned short)(raw & 0xffffu));
        a1[0] += w * bits2f((unsigned short)(raw >> 16));
    }
    for (; j + 8 <= end; j += 8) {
        const uint4 e01 = *(const uint4*)(sorted + j);
        const uint4 e23 = *(const uint4*)(sorted + j + 2);
        const uint4 e45 = *(const uint4*)(sorted + j + 4);
        const uint4 e67 = *(const uint4*)(sorted + j + 6);
        const unsigned r0 = *(const unsigned*)(hb + (size_t)e01.x * NH + lane * 2);
        const unsigned r1 = *(const unsigned*)(hb + (size_t)e01.z * NH + lane * 2);
        const unsigned r2 = *(const unsigned*)(hb + (size_t)e23.x * NH + lane * 2);
        const unsigned r3 = *(const unsigned*)(hb + (size_t)e23.z * NH + lane * 2);
        const unsigned r4 = *(const unsigned*)(hb + (size_t)e45.x * NH + lane * 2);
        const unsigned r5 = *(const unsigned*)(hb + (size_t)e45.z * NH + lane * 2);
        const unsigned r6 = *(const unsigned*)(hb + (size_t)e67.x * NH + lane * 2);
        const unsigned r7 = *(const unsigned*)(hb + (size_t)e67.z * NH + lane * 2);
        const float w0 = __uint_as_float(e01.y), w1 = __uint_as_float(e01.w);
        const float w2 = __uint_as_float(e23.y), w3 = __uint_as_float(e23.w);
        const float w4 = __uint_as_float(e45.y), w5 = __uint_as_float(e45.w);
        const float w6 = __uint_as_float(e67.y), w7 = __uint_as_float(e67.w);
        a0[0] += w0 * bits2f((unsigned short)(r0 & 0xffffu));
        a1[0] += w0 * bits2f((unsigned short)(r0 >> 16));
        a0[1] += w1 * bits2f((unsigned short)(r1 & 0xffffu));
        a1[1] += w1 * bits2f((unsigned short)(r1 >> 16));
        a0[2] += w2 * bits2f((unsigned short)(r2 & 0xffffu));
        a1[2] += w2 * bits2f((unsigned short)(r2 >> 16));
        a0[3] += w3 * bits2f((unsigned short)(r3 & 0xffffu));
        a1[3] += w3 * bits2f((unsigned short)(r3 >> 16));
        a0[4] += w4 * bits2f((unsigned short)(r4 & 0xffffu));
        a1[4] += w4 * bits2f((unsigned short)(r4 >> 16));
        a0[5] += w5 * bits2f((unsigned short)(r5 & 0xffffu));
        a1[5] += w5 * bits2f((unsigned short)(r5 >> 16));
        a0[6] += w6 * bits2f((unsigned short)(r6 & 0xffffu));
        a1[6] += w6 * bits2f((unsigned short)(r6 >> 16));
        a0[7] += w7 * bits2f((unsigned short)(r7 & 0xffffu));
        a1[7] += w7 * bits2f((unsigned short)(r7 >> 16));
    }
    for (; j + 2 <= end; j += 2) {
        const uint4 e01 = *(const uint4*)(sorted + j);
        const unsigned r0 = *(const unsigned*)(hb + (size_t)e01.x * NH + lane * 2);
        const unsigned r1 = *(const unsigned*)(hb + (size_t)e01.z * NH + lane * 2);
        const float w0 = __uint_as_float(e01.y), w1 = __uint_as_float(e01.w);
        a0[0] += w0 * bits2f((unsigned short)(r0 & 0xffffu));
        a1[0] += w0 * bits2f((unsigned short)(r0 >> 16));
        a0[1] += w1 * bits2f((unsigned short)(r1 & 0xffffu));
        a1[1] += w1 * bits2f((unsigned short)(r1 >> 16));
    }
    if (j < end) {
        const uint2 ev = sorted[j];
        const float w = __uint_as_float(ev.y);
        const unsigned raw = *(const unsigned*)(hb + (size_t)ev.x * NH + lane * 2);
        a0[0] += w * bits2f((unsigned short)(raw & 0xffffu));
        a1[0] += w * bits2f((unsigned short)(raw >> 16));
    }
    const float f0 = ((a0[0] + a0[1]) + (a0[2] + a0[3])) + ((a0[4] + a0[5]) + (a0[6] + a0[7]));
    const float f1 = ((a1[0] + a1[1]) + (a1[2] + a1[3])) + ((a1[4] + a1[5]) + (a1[6] + a1[7]));
    unsigned o = ((unsigned)__bfloat16_as_ushort(f2bf(f1)) << 16) |
                 (unsigned)__bfloat16_as_ushort(f2bf(f0));
    *(unsigned*)((unsigned short*)agg + (size_t)node * NH + lane * 2) = o;
}

// ---------------------------------------------------------------------------
// t = agg @ Wrel^T + h @ Wroot^T + b   (bf16 in, fp32 out)
// Register-resident weights. Fused column sum/sumsq -> atomic into stats.
// ---------------------------------------------------------------------------
__global__ __launch_bounds__(256, 2) void gemm_conv_kernel(
    const __hip_bfloat16* __restrict__ agg, const __hip_bfloat16* __restrict__ h,
    const __hip_bfloat16* __restrict__ Wrel, const __hip_bfloat16* __restrict__ Wroot,
    const float* __restrict__ bias, float* __restrict__ out,
    float* __restrict__ stats)
{
    const int waveG = blockIdx.x * 4 + (threadIdx.x >> 6);  // 0..2047
    const int lane = threadIdx.x & 63;
    const int half = waveG & 1;
    const int ar = lane & 15;
    const int q  = lane >> 4;

    bf16x8 brel[4][4], brt[4][4];
    float bv[4];
    #pragma unroll
    for (int t = 0; t < 4; ++t) {
        const int row = half * 64 + t * 16 + ar;
        bv[t] = bias[row];
        #pragma unroll
        for (int k = 0; k < 4; ++k) {
            brel[t][k] = *(const bf16x8*)(Wrel + (size_t)row * NH + k * 32 + q * 8);
            brt[t][k]  = *(const bf16x8*)(Wroot + (size_t)row * NH + k * 32 + q * 8);
        }
    }

    float s1[4] = {}, s2[4] = {};

    for (int strip = waveG >> 1; strip < MTILES; strip += GEMM_BLOCKS * 2) {
        const int m0 = strip << 4;
        floatx4 acc[4] = {};
        #pragma unroll
        for (int k = 0; k < 4; ++k) {
            const bf16x8 a = *(const bf16x8*)(agg + (size_t)(m0 + ar) * NH + k * 32 + q * 8);
            #pragma unroll
            for (int t = 0; t < 4; ++t)
                acc[t] = __builtin_amdgcn_mfma_f32_16x16x32_bf16(a, brel[t][k], acc[t], 0, 0, 0);
        }
        #pragma unroll
        for (int k = 0; k < 4; ++k) {
            const bf16x8 a = *(const bf16x8*)(h + (size_t)(m0 + ar) * NH + k * 32 + q * 8);
            #pragma unroll
            for (int t = 0; t < 4; ++t)
                acc[t] = __builtin_amdgcn_mfma_f32_16x16x32_bf16(a, brt[t][k], acc[t], 0, 0, 0);
        }
        #pragma unroll
        for (int t = 0; t < 4; ++t) {
            const int col = half * 64 + t * 16 + ar;
            #pragma unroll
            for (int r = 0; r < 4; ++r) {
                const float v = acc[t][r] + bv[t];
                out[(size_t)(m0 + q * 4 + r) * NH + col] = v;
                s1[t] += v; s2[t] += v * v;
            }
        }
    }

    __shared__ float sst[256];
    sst[threadIdx.x] = 0.f;
    __syncthreads();
    #pragma unroll
    for (int t = 0; t < 4; ++t) {
        float a = s1[t], b = s2[t];
        a += __shfl_xor(a, 16, 64); a += __shfl_xor(a, 32, 64);
        b += __shfl_xor(b, 16, 64); b += __shfl_xor(b, 32, 64);
        if (q == 0) {
            const int col = half * 64 + t * 16 + ar;
            atomicAdd(&sst[col], a);
            atomicAdd(&sst[128 + col], b);
        }
    }
    __syncthreads();
    unsafeAtomicAdd(&stats[threadIdx.x], sst[threadIdx.x]);
}

// ---------------------------------------------------------------------------
// BN normalize variants
// ---------------------------------------------------------------------------
__global__ __launch_bounds__(256) void bn_relu_bf16_kernel(
    const float* __restrict__ t, const float* __restrict__ stats,
    const float* __restrict__ gamma, const float* __restrict__ beta,
    __hip_bfloat16* __restrict__ out)
{
    const size_t i = (size_t)blockIdx.x * blockDim.x + threadIdx.x;  // exact grid
    const int c = (int)(i & (NH - 1));
    const float inv_n = 1.0f / (float)NNODES;
    const float mu = stats[c] * inv_n;
    const float var = stats[128 + c] * inv_n - mu * mu;
    const float rs = rsqrtf(var + BN_EPS);
    float v = (t[i] - mu) * rs * gamma[c] + beta[c];
    out[i] = f2bf(fmaxf(v, 0.f));
}

__global__ __launch_bounds__(256) void bn_f32_kernel(
    const float* __restrict__ t, const float* __restrict__ stats,
    const float* __restrict__ gamma, const float* __restrict__ beta,
    float* __restrict__ out)
{
    const size_t i = (size_t)blockIdx.x * blockDim.x + threadIdx.x;
    const int c = (int)(i & (NH - 1));
    const float inv_n = 1.0f / (float)NNODES;
    const float mu = stats[c] * inv_n;
    const float var = stats[128 + c] * inv_n - mu * mu;
    const float rs = rsqrtf(var + BN_EPS);
    out[i] = (t[i] - mu) * rs * gamma[c] + beta[c];
}

// ---------------------------------------------------------------------------

extern "C" void kernel_launch(void* const* d_in, const int* in_sizes, int n_in,
                              void* d_out, int out_size, void* d_ws, size_t ws_size,
                              hipStream_t stream)
{
    const float* x    = (const float*)d_in[0];
    const int*   adj  = (const int*)d_in[1];
    const float* ew   = (const float*)d_in[2];
    const float* W_in = (const float*)d_in[3];
    const float* b_in = (const float*)d_in[4];
    const float* W1r  = (const float*)d_in[5];
    const float* b1   = (const float*)d_in[6];
    const float* W1o  = (const float*)d_in[7];
    const float* W2r  = (const float*)d_in[8];
    const float* b2   = (const float*)d_in[9];
    const float* W2o  = (const float*)d_in[10];
    const float* gmm  = (const float*)d_in[11];
    const float* bta  = (const float*)d_in[12];
    float* out = (float*)d_out;          // fp32 output [N, NH]
    float* t   = (float*)d_out;          // pre-BN conv result lives in d_out

    char* ws = (char*)d_ws;
    __hip_bfloat16* h0  = (__hip_bfloat16*)ws; ws += (size_t)NNODES * NH * 2;  // 12.8 MB
    __hip_bfloat16* h1  = (__hip_bfloat16*)ws; ws += (size_t)NNODES * NH * 2;  // 12.8 MB
    __hip_bfloat16* agg = (__hip_bfloat16*)ws; ws += (size_t)NNODES * NH * 2;  // 12.8 MB
    uint2*          sorted  = (uint2*)ws;      ws += (size_t)NBUCKETS * BCAP * 8;  // 7.2 MB
    uint2*          pairbuf = (uint2*)ws;      ws += (size_t)NBUCKETS * BCAP * 8;  // 7.2 MB
    unsigned char*  nodebuf = (unsigned char*)ws; ws += (size_t)NBUCKETS * BCAP;   // 0.9 MB
    int*            rowptr  = (int*)ws;        ws += NNODES * 4;
    int*            rowend  = (int*)ws;        ws += NNODES * 4;
    int*            gcursor = (int*)ws;        ws += ((NBUCKETS + 3) & ~3) * 4;
    __hip_bfloat16* wbf     = (__hip_bfloat16*)ws; ws += 98304 * 2;            // 192 KB
    float*          st1     = (float*)ws;      ws += 256 * 4;
    float*          st2     = (float*)ws;      ws += 256 * 4;

    const __hip_bfloat16* Wb_in = wbf;
    const __hip_bfloat16* Wb1r  = wbf + 32768;
    const __hip_bfloat16* Wb1o  = wbf + 49152;
    const __hip_bfloat16* Wb2r  = wbf + 65536;
    const __hip_bfloat16* Wb2o  = wbf + 81920;

    const int node_blocks = (NNODES + 3) / 4;                   // 12500
    const int bn_blocks   = (NNODES * NH) / 256;                // 25000

    // ---- prep: weight conversion (+ cursor/stats init) + bucket CSR ----
    convert_w_kernel<<<98304 / 256, 256, 0, stream>>>(W_in, W1r, W1o, W2r, W2o,
                                                      wbf, gcursor, st1, st2);
    bucket_scatter_kernel<<<SCAT_BLOCKS, 256, 0, stream>>>(adj, ew, gcursor, pairbuf, nodebuf);
    bucket_sort_kernel<<<NBUCKETS, 256, 0, stream>>>(gcursor, pairbuf, nodebuf,
                                                     sorted, rowptr, rowend);

    // ---- layer 1 ----
    gemm_in_kernel<<<GEMM_BLOCKS, 256, 0, stream>>>(x, Wb_in, b_in, h0);
    gather_kernel<<<node_blocks, 256, 0, stream>>>(sorted, rowptr, rowend, h0, agg);
    gemm_conv_kernel<<<GEMM_BLOCKS, 256, 0, stream>>>(agg, h0, Wb1r, Wb1o, b1, t, st1);
    bn_relu_bf16_kernel<<<bn_blocks, 256, 0, stream>>>(t, st1, gmm, bta, h1);

    // ---- layer 2 ----
    gather_kernel<<<node_blocks, 256, 0, stream>>>(sorted, rowptr, rowend, h1, agg);
    gemm_conv_kernel<<<GEMM_BLOCKS, 256, 0, stream>>>(agg, h1, Wb2r, Wb2o, b2, t, st2);
    bn_f32_kernel<<<bn_blocks, 256, 0, stream>>>(t, st2, gmm, bta, out);
}